// Round 1
// baseline (875.012 us; speedup 1.0000x reference)
//
#include <hip/hip_runtime.h>
#include <math.h>

#define EPS 1e-5f
#define ROWS 4096   // B*N

// ---------------------------------------------------------------------------
// Per-row mean / rstd over 512 columns (LayerNorm stats). 1 wave per row.
// ---------------------------------------------------------------------------
__global__ void row_stats512(const float* __restrict__ x,
                             float* __restrict__ mean, float* __restrict__ rstd) {
    int row = blockIdx.x;
    int lane = threadIdx.x; // 64
    const float* xr = x + (size_t)row * 512;
    float s = 0.f, sq = 0.f;
#pragma unroll
    for (int u = 0; u < 2; ++u) {
        float4 v = *(const float4*)(xr + lane * 4 + u * 256);
        s += v.x + v.y + v.z + v.w;
        sq += v.x * v.x + v.y * v.y + v.z * v.z + v.w * v.w;
    }
#pragma unroll
    for (int off = 32; off; off >>= 1) {
        s += __shfl_xor(s, off);
        sq += __shfl_xor(sq, off);
    }
    if (lane == 0) {
        float m = s * (1.f / 512.f);
        float var = sq * (1.f / 512.f) - m * m;
        mean[row] = m;
        rstd[row] = rsqrtf(var + EPS);
    }
}

// ---------------------------------------------------------------------------
// Generic NT GEMM: C[M,N] = A[M,K] (optionally LayerNormed) @ B[N,K]^T
// EPI: 0 none, 1 +bias, 2 +bias+resid, 3 gelu(x+bias)
// Tile 128x64x16, 256 threads, 8x4 microtile.
// ---------------------------------------------------------------------------
template <bool LNA, int EPI>
__global__ __launch_bounds__(256) void gemm_nt(
    const float* __restrict__ A, const float* __restrict__ Bm,
    float* __restrict__ C, int M, int N, int K,
    const float* __restrict__ bias, const float* __restrict__ resid,
    const float* __restrict__ lnMean, const float* __restrict__ lnRstd,
    const float* __restrict__ lnG, const float* __restrict__ lnB) {
    __shared__ float As[16 * 132];
    __shared__ float Bs[16 * 68];
    int t = threadIdx.x;
    int m0 = blockIdx.y * 128;
    int n0 = blockIdx.x * 64;
    int tx = t & 15, ty = t >> 4;
    float acc[8][4];
#pragma unroll
    for (int i = 0; i < 8; ++i)
#pragma unroll
        for (int j = 0; j < 4; ++j) acc[i][j] = 0.f;

    int arow = t >> 1, akp = (t & 1) * 8;
    int brow = t >> 2, bkp = (t & 3) * 4;
    const float* Aptr = A + (size_t)(m0 + arow) * K + akp;
    const float* Bptr = Bm + (size_t)(n0 + brow) * K + bkp;
    float lm = 0.f, lr = 0.f;
    if (LNA) {
        lm = lnMean[m0 + arow];
        lr = lnRstd[m0 + arow];
    }

    for (int k0 = 0; k0 < K; k0 += 16) {
#pragma unroll
        for (int u = 0; u < 2; ++u) {
            float4 v = *(const float4*)(Aptr + k0 + u * 4);
            if (LNA) {
                float4 g = *(const float4*)(lnG + k0 + akp + u * 4);
                float4 bb = *(const float4*)(lnB + k0 + akp + u * 4);
                v.x = (v.x - lm) * lr * g.x + bb.x;
                v.y = (v.y - lm) * lr * g.y + bb.y;
                v.z = (v.z - lm) * lr * g.z + bb.z;
                v.w = (v.w - lm) * lr * g.w + bb.w;
            }
            As[(akp + u * 4 + 0) * 132 + arow] = v.x;
            As[(akp + u * 4 + 1) * 132 + arow] = v.y;
            As[(akp + u * 4 + 2) * 132 + arow] = v.z;
            As[(akp + u * 4 + 3) * 132 + arow] = v.w;
        }
        {
            float4 v = *(const float4*)(Bptr + k0);
            Bs[(bkp + 0) * 68 + brow] = v.x;
            Bs[(bkp + 1) * 68 + brow] = v.y;
            Bs[(bkp + 2) * 68 + brow] = v.z;
            Bs[(bkp + 3) * 68 + brow] = v.w;
        }
        __syncthreads();
#pragma unroll
        for (int kk = 0; kk < 16; ++kk) {
            float4 a0 = *(const float4*)&As[kk * 132 + ty * 8];
            float4 a1 = *(const float4*)&As[kk * 132 + ty * 8 + 4];
            float4 b0 = *(const float4*)&Bs[kk * 68 + tx * 4];
            float a[8] = {a0.x, a0.y, a0.z, a0.w, a1.x, a1.y, a1.z, a1.w};
            float b[4] = {b0.x, b0.y, b0.z, b0.w};
#pragma unroll
            for (int i = 0; i < 8; ++i)
#pragma unroll
                for (int j = 0; j < 4; ++j) acc[i][j] += a[i] * b[j];
        }
        __syncthreads();
    }

#pragma unroll
    for (int i = 0; i < 8; ++i) {
        int r = m0 + ty * 8 + i;
        float* Cr = C + (size_t)r * N + n0 + tx * 4;
#pragma unroll
        for (int j = 0; j < 4; ++j) {
            float v = acc[i][j];
            if (EPI >= 1) v += bias[n0 + tx * 4 + j];
            if (EPI == 2) v += resid[(size_t)r * N + n0 + tx * 4 + j];
            if (EPI == 3) v = 0.5f * v * (1.f + erff(v * 0.70710678118654752f));
            Cr[j] = v;
        }
    }
}

// ---------------------------------------------------------------------------
// Per (head,row) stats of projected features: mean, 1/norm, var(ddof=1).
// block = 512 threads (8 waves = 8 heads), grid = 4096 rows.
// ---------------------------------------------------------------------------
__global__ void head_stats(const float* __restrict__ f, float* __restrict__ meanO,
                           float* __restrict__ rnormO, float* __restrict__ varO) {
    int row = blockIdx.x;
    int t = threadIdx.x;
    int h = t >> 6, lane = t & 63;
    float v = f[(size_t)row * 512 + t];
    float s = v, sq = v * v;
#pragma unroll
    for (int off = 32; off; off >>= 1) {
        s += __shfl_xor(s, off);
        sq += __shfl_xor(sq, off);
    }
    if (lane == 0) {
        float m = s * (1.f / 64.f);
        int idx = h * ROWS + row;
        meanO[idx] = m;
        rnormO[idx] = rsqrtf(sq);
        varO[idx] = (sq - 64.f * m * m) * (1.f / 63.f);
    }
}

__global__ void zero_k(float* __restrict__ p, int n) {
    int i = blockIdx.x * blockDim.x + threadIdx.x;
    if (i < n) p[i] = 0.f;
}

// Column means of fq/fk over all 4096 rows -> qg/kg [512].
__global__ void colmean(const float* __restrict__ fq, const float* __restrict__ fk,
                        float* __restrict__ qg, float* __restrict__ kg) {
    int tensor = blockIdx.x >> 3, chunk = blockIdx.x & 7;
    const float* f = tensor ? fk : fq;
    float* o = tensor ? kg : qg;
    int col = threadIdx.x;  // 512
    float s = 0.f;
    int r0 = chunk * 512;
    for (int r = 0; r < 512; ++r) s += f[(size_t)(r0 + r) * 512 + col];
    atomicAdd(&o[col], s * (1.f / 4096.f));
}

// Tiny policy MLP: w[h,3] = softmax(relu(LN(feats@W1^T+b1))@W2^T + b2)
__global__ void policy_mlp(const float* __restrict__ qg, const float* __restrict__ kg,
                           const float* __restrict__ W1, const float* __restrict__ b1,
                           const float* __restrict__ g, const float* __restrict__ bb,
                           const float* __restrict__ W2, const float* __restrict__ b2,
                           float* __restrict__ wmix) {
    int h = blockIdx.x, j = threadIdx.x;  // 64
    float acc = 0.f;
    const float* w1r = W1 + j * 128;
    for (int i = 0; i < 64; ++i) acc += qg[h * 64 + i] * w1r[i];
    for (int i = 0; i < 64; ++i) acc += kg[h * 64 + i] * w1r[64 + i];
    acc += b1[j];
    float s = acc, sq = acc * acc;
#pragma unroll
    for (int off = 32; off; off >>= 1) {
        s += __shfl_xor(s, off);
        sq += __shfl_xor(sq, off);
    }
    float m = s * (1.f / 64.f);
    float var = sq * (1.f / 64.f) - m * m;
    float xh = (acc - m) * rsqrtf(var + EPS) * g[j] + bb[j];
    float r = fmaxf(xh, 0.f);
    float l[3];
#pragma unroll
    for (int c = 0; c < 3; ++c) {
        float p = r * W2[c * 64 + j];
#pragma unroll
        for (int off = 32; off; off >>= 1) p += __shfl_xor(p, off);
        l[c] = p + b2[c];
    }
    if (j == 0) {
        float mx = fmaxf(l[0], fmaxf(l[1], l[2]));
        float e0 = expf(l[0] - mx), e1 = expf(l[1] - mx), e2 = expf(l[2] - mx);
        float inv = 1.f / (e0 + e1 + e2);
        wmix[h * 3 + 0] = e0 * inv;
        wmix[h * 3 + 1] = e1 * inv;
        wmix[h * 3 + 2] = e2 * inv;
    }
}

// ---------------------------------------------------------------------------
// K-side reduction per (h,b): M1 = (K*rnk)^T V, M2 = K^T V (64x64 each),
// Skv = sum_m kv[m] v[m,:], Smk = sum_m mk[m] v[m,:].
// ---------------------------------------------------------------------------
__global__ __launch_bounds__(256) void kside(
    const float* __restrict__ fk, const float* __restrict__ fv,
    const float* __restrict__ rnk, const float* __restrict__ kvv,
    const float* __restrict__ mk, float* __restrict__ Mbuf) {
    int hb = blockIdx.x;
    int h = hb >> 2, b = hb & 3;
    __shared__ float fkt[32 * 64];
    __shared__ float fvt[32 * 64];
    __shared__ float rs[32], kvs[32], mks[32];
    int t = threadIdx.x;
    int td = t >> 4, te = t & 15;
    float m1[4][4] = {}, m2[4][4] = {};
    float skv = 0.f, smk = 0.f;
    for (int m0 = 0; m0 < 1024; m0 += 32) {
#pragma unroll
        for (int u = 0; u < 8; ++u) {
            int idx = t + u * 256;
            int mm = idx >> 6, d = idx & 63;
            size_t grow = (size_t)(b * 1024 + m0 + mm) * 512 + h * 64 + d;
            fkt[idx] = fk[grow];
            fvt[idx] = fv[grow];
        }
        if (t < 32) {
            int sidx = h * ROWS + b * 1024 + m0 + t;
            rs[t] = rnk[sidx];
            kvs[t] = kvv[sidx];
            mks[t] = mk[sidx];
        }
        __syncthreads();
        for (int mi = 0; mi < 32; ++mi) {
            float r = rs[mi];
            float kreg[4], vreg[4], krr[4];
#pragma unroll
            for (int i = 0; i < 4; ++i) kreg[i] = fkt[mi * 64 + td * 4 + i];
#pragma unroll
            for (int j = 0; j < 4; ++j) vreg[j] = fvt[mi * 64 + te * 4 + j];
#pragma unroll
            for (int i = 0; i < 4; ++i) krr[i] = kreg[i] * r;
#pragma unroll
            for (int i = 0; i < 4; ++i)
#pragma unroll
                for (int j = 0; j < 4; ++j) {
                    m2[i][j] += kreg[i] * vreg[j];
                    m1[i][j] += krr[i] * vreg[j];
                }
            if (t < 64) {
                skv += kvs[mi] * fvt[mi * 64 + t];
                smk += mks[mi] * fvt[mi * 64 + t];
            }
        }
        __syncthreads();
    }
    float* base = Mbuf + (size_t)hb * 8320;
#pragma unroll
    for (int i = 0; i < 4; ++i)
#pragma unroll
        for (int j = 0; j < 4; ++j) {
            base[(td * 4 + i) * 64 + te * 4 + j] = m1[i][j];
            base[4096 + (td * 4 + i) * 64 + te * 4 + j] = m2[i][j];
        }
    if (t < 64) {
        base[8192 + t] = skv;
        base[8256 + t] = smk;
    }
}

// ---------------------------------------------------------------------------
// Q-side: attn_out[n, h*64+e] = cw*rnq[n]*(fq@M1)[e] + (covw/64)*(fq@M2)[e]
//                               + (vw/64)*qv[n]*Skv[e] - covw*mq[n]*Smk[e]
// ---------------------------------------------------------------------------
__global__ __launch_bounds__(256) void qside(
    const float* __restrict__ fq, const float* __restrict__ Mbuf,
    const float* __restrict__ rnq, const float* __restrict__ mq,
    const float* __restrict__ qv, const float* __restrict__ wmix,
    float* __restrict__ attn_out) {
    int ntile = blockIdx.x, hb = blockIdx.y;
    int h = hb >> 2, b = hb & 3;
    __shared__ float M1s[4096], M2s[4096], fqt[16 * 64], Skvs[64], Smks[64];
    __shared__ float rnqs[16], mqs[16], qvs[16];
    int t = threadIdx.x;
    const float* base = Mbuf + (size_t)hb * 8320;
#pragma unroll
    for (int u = 0; u < 16; ++u) {
        M1s[t + u * 256] = base[t + u * 256];
        M2s[t + u * 256] = base[4096 + t + u * 256];
    }
    if (t < 64) {
        Skvs[t] = base[8192 + t];
        Smks[t] = base[8256 + t];
    }
    int n0 = ntile * 16;
#pragma unroll
    for (int u = 0; u < 4; ++u) {
        int idx = t + u * 256;
        int r = idx >> 6, d = idx & 63;
        fqt[idx] = fq[(size_t)(b * 1024 + n0 + r) * 512 + h * 64 + d];
    }
    if (t < 16) {
        int sidx = h * ROWS + b * 1024 + n0 + t;
        rnqs[t] = rnq[sidx];
        mqs[t] = mq[sidx];
        qvs[t] = qv[sidx];
    }
    __syncthreads();
    float cw = wmix[h * 3 + 0], covw = wmix[h * 3 + 1], vw = wmix[h * 3 + 2];
    int e = t & 63, rq = t >> 6;
    float a1[4] = {}, a2[4] = {};
    for (int d = 0; d < 64; ++d) {
        float m1v = M1s[d * 64 + e], m2v = M2s[d * 64 + e];
#pragma unroll
        for (int i = 0; i < 4; ++i) {
            float qd = fqt[(rq * 4 + i) * 64 + d];
            a1[i] += qd * m1v;
            a2[i] += qd * m2v;
        }
    }
    float c2 = covw * (1.f / 64.f), c3 = vw * (1.f / 64.f);
#pragma unroll
    for (int i = 0; i < 4; ++i) {
        int rr = rq * 4 + i;
        float v = cw * rnqs[rr] * a1[i] + c2 * a2[i] + c3 * qvs[rr] * Skvs[e] -
                  covw * mqs[rr] * Smks[e];
        attn_out[(size_t)(b * 1024 + n0 + rr) * 512 + h * 64 + e] = v;
    }
}

// ---------------------------------------------------------------------------
extern "C" void kernel_launch(void* const* d_in, const int* in_sizes, int n_in,
                              void* d_out, int out_size, void* d_ws, size_t ws_size,
                              hipStream_t stream) {
    const float* q = (const float*)d_in[0];
    const float* k = (const float*)d_in[1];
    const float* v = (const float*)d_in[2];
    const float* Win = (const float*)d_in[3];
    const float* Wout = (const float*)d_in[4];
    const float* bout = (const float*)d_in[5];
    const float* g1 = (const float*)d_in[6];
    const float* b1n = (const float*)d_in[7];
    const float* g2 = (const float*)d_in[8];
    const float* b2n = (const float*)d_in[9];
    const float* Wup = (const float*)d_in[10];
    const float* bup = (const float*)d_in[11];
    const float* Wdn = (const float*)d_in[12];
    const float* bdn = (const float*)d_in[13];
    const float* wpW1 = (const float*)d_in[14];
    const float* wpb1 = (const float*)d_in[15];
    const float* wpg = (const float*)d_in[16];
    const float* wpb = (const float*)d_in[17];
    const float* wpW2 = (const float*)d_in[18];
    const float* wpb2 = (const float*)d_in[19];
    float* out = (float*)d_out;

    float* wsf = (float*)d_ws;
    // region [0, 8388608) : fq,fk,fv (first 6.3M) ... later reused as hmid
    float* fq = wsf;
    float* fk = wsf + 2097152;
    float* fv = wsf + 2 * 2097152;
    float* hmid = wsf;  // 4096*2048, reuses fq/fk/fv after attention is done
    float* attn = wsf + 8388608;  // 2097152
    float* p = wsf + 8388608 + 2097152;
    float* meanq = p; p += 4096;
    float* rstdq = p; p += 4096;
    float* meank = p; p += 4096;
    float* rstdk = p; p += 4096;
    float* meanv = p; p += 4096;
    float* rstdv = p; p += 4096;
    float* mean2 = p; p += 4096;
    float* rstd2 = p; p += 4096;
    float* mqS = p; p += 32768;
    float* rnqS = p; p += 32768;
    float* qvS = p; p += 32768;
    float* mkS = p; p += 32768;
    float* rnkS = p; p += 32768;
    float* kvS = p; p += 32768;
    float* qg = p; p += 512;
    float* kg = p; p += 512;
    float* wmix = p; p += 32;
    float* Mbuf = p; p += 32 * 8320;

    // 1. LN stats for q,k,v
    row_stats512<<<4096, 64, 0, stream>>>(q, meanq, rstdq);
    row_stats512<<<4096, 64, 0, stream>>>(k, meank, rstdk);
    row_stats512<<<4096, 64, 0, stream>>>(v, meanv, rstdv);

    // 2. fused LN + projection: f = LN(x) @ Win^T
    dim3 gproj(512 / 64, 4096 / 128);
    gemm_nt<true, 0><<<gproj, 256, 0, stream>>>(q, Win, fq, 4096, 512, 512,
                                                nullptr, nullptr, meanq, rstdq, g1, b1n);
    gemm_nt<true, 0><<<gproj, 256, 0, stream>>>(k, Win, fk, 4096, 512, 512,
                                                nullptr, nullptr, meank, rstdk, g1, b1n);
    gemm_nt<true, 0><<<gproj, 256, 0, stream>>>(v, Win, fv, 4096, 512, 512,
                                                nullptr, nullptr, meanv, rstdv, g1, b1n);

    // 3. per-(head,row) stats
    head_stats<<<4096, 512, 0, stream>>>(fq, mqS, rnqS, qvS);
    head_stats<<<4096, 512, 0, stream>>>(fk, mkS, rnkS, kvS);

    // 4. global per-head means + policy MLP -> mixing weights
    zero_k<<<4, 256, 0, stream>>>(qg, 1024);  // qg and kg are contiguous
    colmean<<<16, 512, 0, stream>>>(fq, fk, qg, kg);
    policy_mlp<<<8, 64, 0, stream>>>(qg, kg, wpW1, wpb1, wpg, wpb, wpW2, wpb2, wmix);

    // 5. K-side 64x64 reductions, then Q-side apply (linear-attention trick)
    kside<<<32, 256, 0, stream>>>(fk, fv, rnkS, kvS, mkS, Mbuf);
    qside<<<dim3(64, 32), 256, 0, stream>>>(fq, Mbuf, rnqS, mqS, qvS, wmix, attn);

    // 6. q2 = q + attn @ Wout^T + bout   (q2 lives in d_out)
    gemm_nt<false, 2><<<gproj, 256, 0, stream>>>(attn, Wout, out, 4096, 512, 512,
                                                 bout, q, nullptr, nullptr, nullptr, nullptr);

    // 7. MLP: y = gelu(LN(q2)@Wup^T+bup) @ Wdn^T + bdn ; out = q2 + y
    row_stats512<<<4096, 64, 0, stream>>>(out, mean2, rstd2);
    gemm_nt<true, 3><<<dim3(2048 / 64, 4096 / 128), 256, 0, stream>>>(
        out, Wup, hmid, 4096, 2048, 512, bup, nullptr, mean2, rstd2, g2, b2n);
    gemm_nt<false, 2><<<dim3(512 / 64, 4096 / 128), 256, 0, stream>>>(
        hmid, Wdn, out, 4096, 512, 2048, bdn, out, nullptr, nullptr, nullptr, nullptr);
}

// Round 2
// 313.636 us; speedup vs baseline: 2.7899x; 2.7899x over previous
//
#include <hip/hip_runtime.h>
#include <math.h>

#define EPS 1e-5f
#define ROWS 4096  // B*N

typedef __attribute__((ext_vector_type(8))) short short8;
typedef __attribute__((ext_vector_type(4))) float floatx4;

__device__ inline short f2bf(float f) {
    unsigned u = __builtin_bit_cast(unsigned, f);
    unsigned r = (u + 0x7fffu + ((u >> 16) & 1u)) >> 16;
    return (short)r;
}

// ---------------------------------------------------------------------------
// Fused LayerNorm + bf16 convert. grid (1024, T): block = 256 thr = 4 rows.
// Row handled by one wave (64 lanes x 8 elems = 512). Writes stacked bf16.
// ---------------------------------------------------------------------------
__global__ __launch_bounds__(256) void lnconv(
    const float* __restrict__ x0, const float* __restrict__ x1,
    const float* __restrict__ x2, const float* __restrict__ g,
    const float* __restrict__ bb, short* __restrict__ out) {
    int tensor = blockIdx.y;
    const float* x = tensor == 0 ? x0 : (tensor == 1 ? x1 : x2);
    int t = threadIdx.x;
    int row = blockIdx.x * 4 + (t >> 6);
    int col = (t & 63) * 8;
    const float* xr = x + (size_t)row * 512 + col;
    float4 v0 = *(const float4*)xr;
    float4 v1 = *(const float4*)(xr + 4);
    float s = v0.x + v0.y + v0.z + v0.w + v1.x + v1.y + v1.z + v1.w;
    float sq = v0.x * v0.x + v0.y * v0.y + v0.z * v0.z + v0.w * v0.w +
               v1.x * v1.x + v1.y * v1.y + v1.z * v1.z + v1.w * v1.w;
#pragma unroll
    for (int off = 32; off; off >>= 1) {
        s += __shfl_xor(s, off);
        sq += __shfl_xor(sq, off);
    }
    float m = s * (1.f / 512.f);
    float rstd = rsqrtf(sq * (1.f / 512.f) - m * m + EPS);
    float4 g0 = *(const float4*)(g + col);
    float4 g1 = *(const float4*)(g + col + 4);
    float4 b0 = *(const float4*)(bb + col);
    float4 b1 = *(const float4*)(bb + col + 4);
    short8 o;
    o[0] = f2bf((v0.x - m) * rstd * g0.x + b0.x);
    o[1] = f2bf((v0.y - m) * rstd * g0.y + b0.y);
    o[2] = f2bf((v0.z - m) * rstd * g0.z + b0.z);
    o[3] = f2bf((v0.w - m) * rstd * g0.w + b0.w);
    o[4] = f2bf((v1.x - m) * rstd * g1.x + b1.x);
    o[5] = f2bf((v1.y - m) * rstd * g1.y + b1.y);
    o[6] = f2bf((v1.z - m) * rstd * g1.z + b1.z);
    o[7] = f2bf((v1.w - m) * rstd * g1.w + b1.w);
    *(short8*)(out + (size_t)(tensor * 4096 + row) * 512 + col) = o;
}

// ---------------------------------------------------------------------------
// fp32 -> bf16 weight conversion, 4 tensors selected by blockIdx.y.
// ---------------------------------------------------------------------------
__global__ void wconv(const float* __restrict__ w0, const float* __restrict__ w1,
                      const float* __restrict__ w2, const float* __restrict__ w3,
                      short* __restrict__ o0, short* __restrict__ o1,
                      short* __restrict__ o2, short* __restrict__ o3) {
    int y = blockIdx.y;
    const float* src = y == 0 ? w0 : (y == 1 ? w1 : (y == 2 ? w2 : w3));
    short* dst = y == 0 ? o0 : (y == 1 ? o1 : (y == 2 ? o2 : o3));
    int n = (y < 2) ? 262144 : 1048576;
    int idx = (blockIdx.x * 256 + threadIdx.x) * 8;
    if (idx < n) {
        float4 v0 = *(const float4*)(src + idx);
        float4 v1 = *(const float4*)(src + idx + 4);
        short8 o;
        o[0] = f2bf(v0.x); o[1] = f2bf(v0.y); o[2] = f2bf(v0.z); o[3] = f2bf(v0.w);
        o[4] = f2bf(v1.x); o[5] = f2bf(v1.y); o[6] = f2bf(v1.z); o[7] = f2bf(v1.w);
        *(short8*)(dst + idx) = o;
    }
}

// ---------------------------------------------------------------------------
// bf16 MFMA NT GEMM (m97 structure): C[M,N] = A[M,K] @ B[N,K]^T
// 128x128 tile, 4 waves (2x2 of 64x64), 16x16x32 MFMA, BK=32,
// global_load_lds width-16 staging.
// EPI: 0 plain, 2 +bias+resid, 3 gelu(x+bias).  OUT_BF16 selects C dtype.
// ---------------------------------------------------------------------------
template <int EPI, bool OUT_BF16>
__global__ __launch_bounds__(256) void mfma_gemm_nt(
    const short* __restrict__ A, const short* __restrict__ B,
    void* __restrict__ C, int M, int N, int K,
    const float* __restrict__ bias, const float* __restrict__ resid) {
    __shared__ short As[128 * 32];
    __shared__ short Bs[128 * 32];
    int t = threadIdx.x;
    int m0 = blockIdx.y * 128, n0 = blockIdx.x * 128;
    int w = t >> 6, lane = t & 63;
    int wm = (w & 1) * 64, wn = (w >> 1) * 64;
    floatx4 acc[4][4];
#pragma unroll
    for (int i = 0; i < 4; ++i)
#pragma unroll
        for (int j = 0; j < 4; ++j) acc[i][j] = (floatx4){0.f, 0.f, 0.f, 0.f};

    int arow = t >> 2, acol = (t & 3) * 8;
    const short* Ag = A + (size_t)(m0 + arow) * K + acol;
    const short* Bg = B + (size_t)(n0 + arow) * K + acol;
    int ldsbase = w * 1024;  // bytes, wave-uniform

    for (int k0 = 0; k0 < K; k0 += 32) {
        __syncthreads();
#pragma unroll
        for (int u = 0; u < 2; ++u) {
            __builtin_amdgcn_global_load_lds(
                (const __attribute__((address_space(1))) void*)(Ag + (size_t)u * 64 * K + k0),
                (__attribute__((address_space(3))) void*)((char*)As + u * 4096 + ldsbase),
                16, 0, 0);
            __builtin_amdgcn_global_load_lds(
                (const __attribute__((address_space(1))) void*)(Bg + (size_t)u * 64 * K + k0),
                (__attribute__((address_space(3))) void*)((char*)Bs + u * 4096 + ldsbase),
                16, 0, 0);
        }
        __syncthreads();
        int krow = (lane >> 4) * 8;
        short8 af[4], bf[4];
#pragma unroll
        for (int i = 0; i < 4; ++i)
            af[i] = *(const short8*)&As[(wm + i * 16 + (lane & 15)) * 32 + krow];
#pragma unroll
        for (int j = 0; j < 4; ++j)
            bf[j] = *(const short8*)&Bs[(wn + j * 16 + (lane & 15)) * 32 + krow];
#pragma unroll
        for (int i = 0; i < 4; ++i)
#pragma unroll
            for (int j = 0; j < 4; ++j)
                acc[i][j] = __builtin_amdgcn_mfma_f32_16x16x32_bf16(
                    af[i], bf[j], acc[i][j], 0, 0, 0);
    }

    int col = lane & 15, rbase = (lane >> 4) * 4;
#pragma unroll
    for (int i = 0; i < 4; ++i) {
#pragma unroll
        for (int j = 0; j < 4; ++j) {
            int gcol = n0 + wn + j * 16 + col;
#pragma unroll
            for (int r = 0; r < 4; ++r) {
                int grow = m0 + wm + i * 16 + rbase + r;
                float v = acc[i][j][r];
                if (EPI == 2) v += bias[gcol] + resid[(size_t)grow * N + gcol];
                if (EPI == 3) {
                    v += bias[gcol];
                    v = 0.5f * v * (1.f + erff(v * 0.70710678118654752f));
                }
                if (OUT_BF16)
                    ((short*)C)[(size_t)grow * N + gcol] = f2bf(v);
                else
                    ((float*)C)[(size_t)grow * N + gcol] = v;
            }
        }
    }
}

// ---------------------------------------------------------------------------
// Per (head,row) stats: mean, 1/norm, var(ddof=1). grid (4096, 2) y: fq/fk.
// ---------------------------------------------------------------------------
__global__ void head_stats2(const float* __restrict__ fq, const float* __restrict__ fk,
                            float* __restrict__ S) {
    int row = blockIdx.x;
    int y = blockIdx.y;
    const float* f = y ? fk : fq;
    float* base = S + (size_t)y * 98304;
    int t = threadIdx.x;
    int h = t >> 6, lane = t & 63;
    float v = f[(size_t)row * 512 + t];
    float s = v, sq = v * v;
#pragma unroll
    for (int off = 32; off; off >>= 1) {
        s += __shfl_xor(s, off);
        sq += __shfl_xor(sq, off);
    }
    if (lane == 0) {
        float m = s * (1.f / 64.f);
        int idx = h * ROWS + row;
        base[idx] = m;                                 // mean
        base[32768 + idx] = rsqrtf(sq);                // 1/norm
        base[65536 + idx] = (sq - 64.f * m * m) * (1.f / 63.f);  // var
    }
}

__global__ void zero_k(float* __restrict__ p, int n) {
    int i = blockIdx.x * blockDim.x + threadIdx.x;
    if (i < n) p[i] = 0.f;
}

// Column means of fq/fk over 4096 rows. grid (32, 2), 512 thr.
__global__ void colmean(const float* __restrict__ fq, const float* __restrict__ fk,
                        float* __restrict__ qg, float* __restrict__ kg) {
    int tensor = blockIdx.y;
    const float* f = tensor ? fk : fq;
    float* o = tensor ? kg : qg;
    int col = threadIdx.x;
    int r0 = blockIdx.x * 128;
    float s = 0.f;
    for (int r = 0; r < 128; ++r) s += f[(size_t)(r0 + r) * 512 + col];
    atomicAdd(&o[col], s * (1.f / 4096.f));
}

// Tiny policy MLP: w[h,3] = softmax(relu(LN(feats@W1^T+b1))@W2^T + b2)
__global__ void policy_mlp(const float* __restrict__ qg, const float* __restrict__ kg,
                           const float* __restrict__ W1, const float* __restrict__ b1,
                           const float* __restrict__ g, const float* __restrict__ bb,
                           const float* __restrict__ W2, const float* __restrict__ b2,
                           float* __restrict__ wmix) {
    int h = blockIdx.x, j = threadIdx.x;  // 64
    float acc = 0.f;
    const float* w1r = W1 + j * 128;
    for (int i = 0; i < 64; ++i) acc += qg[h * 64 + i] * w1r[i];
    for (int i = 0; i < 64; ++i) acc += kg[h * 64 + i] * w1r[64 + i];
    acc += b1[j];
    float s = acc, sq = acc * acc;
#pragma unroll
    for (int off = 32; off; off >>= 1) {
        s += __shfl_xor(s, off);
        sq += __shfl_xor(sq, off);
    }
    float m = s * (1.f / 64.f);
    float var = sq * (1.f / 64.f) - m * m;
    float xh = (acc - m) * rsqrtf(var + EPS) * g[j] + bb[j];
    float r = fmaxf(xh, 0.f);
    float l[3];
#pragma unroll
    for (int c = 0; c < 3; ++c) {
        float p = r * W2[c * 64 + j];
#pragma unroll
        for (int off = 32; off; off >>= 1) p += __shfl_xor(p, off);
        l[c] = p + b2[c];
    }
    if (j == 0) {
        float mx = fmaxf(l[0], fmaxf(l[1], l[2]));
        float e0 = expf(l[0] - mx), e1 = expf(l[1] - mx), e2 = expf(l[2] - mx);
        float inv = 1.f / (e0 + e1 + e2);
        wmix[h * 3 + 0] = e0 * inv;
        wmix[h * 3 + 1] = e1 * inv;
        wmix[h * 3 + 2] = e2 * inv;
    }
}

// ---------------------------------------------------------------------------
// K-side partial reduction per (h,b,chunk): M1=(K*rnk)^T V, M2=K^T V,
// Skv=sum kv*v, Smk=sum mk*v over 256 rows. grid (32, 4).
// ---------------------------------------------------------------------------
__global__ __launch_bounds__(256) void ksideP(
    const float* __restrict__ fk, const float* __restrict__ fv,
    const float* __restrict__ rnk, const float* __restrict__ kvv,
    const float* __restrict__ mk, float* __restrict__ Mpart) {
    int hb = blockIdx.x;
    int chunk = blockIdx.y;
    int h = hb >> 2, b = hb & 3;
    __shared__ float fkt[32 * 64];
    __shared__ float fvt[32 * 64];
    __shared__ float rs[32], kvs[32], mks[32];
    int t = threadIdx.x;
    int td = t >> 4, te = t & 15;
    float m1[4][4] = {}, m2[4][4] = {};
    float skv = 0.f, smk = 0.f;
    int mstart = chunk * 256;
    for (int m0 = mstart; m0 < mstart + 256; m0 += 32) {
#pragma unroll
        for (int u = 0; u < 8; ++u) {
            int idx = t + u * 256;
            int mm = idx >> 6, d = idx & 63;
            size_t grow = (size_t)(b * 1024 + m0 + mm) * 512 + h * 64 + d;
            fkt[idx] = fk[grow];
            fvt[idx] = fv[grow];
        }
        if (t < 32) {
            int sidx = h * ROWS + b * 1024 + m0 + t;
            rs[t] = rnk[sidx];
            kvs[t] = kvv[sidx];
            mks[t] = mk[sidx];
        }
        __syncthreads();
        for (int mi = 0; mi < 32; ++mi) {
            float r = rs[mi];
            float kreg[4], vreg[4], krr[4];
#pragma unroll
            for (int i = 0; i < 4; ++i) kreg[i] = fkt[mi * 64 + td * 4 + i];
#pragma unroll
            for (int j = 0; j < 4; ++j) vreg[j] = fvt[mi * 64 + te * 4 + j];
#pragma unroll
            for (int i = 0; i < 4; ++i) krr[i] = kreg[i] * r;
#pragma unroll
            for (int i = 0; i < 4; ++i)
#pragma unroll
                for (int j = 0; j < 4; ++j) {
                    m2[i][j] += kreg[i] * vreg[j];
                    m1[i][j] += krr[i] * vreg[j];
                }
            if (t < 64) {
                skv += kvs[mi] * fvt[mi * 64 + t];
                smk += mks[mi] * fvt[mi * 64 + t];
            }
        }
        __syncthreads();
    }
    float* base = Mpart + (size_t)(chunk * 32 + hb) * 8320;
#pragma unroll
    for (int i = 0; i < 4; ++i)
#pragma unroll
        for (int j = 0; j < 4; ++j) {
            base[(td * 4 + i) * 64 + te * 4 + j] = m1[i][j];
            base[4096 + (td * 4 + i) * 64 + te * 4 + j] = m2[i][j];
        }
    if (t < 64) {
        base[8192 + t] = skv;
        base[8256 + t] = smk;
    }
}

__global__ void reduceM(const float* __restrict__ Mpart, float* __restrict__ Mbuf) {
    int i = blockIdx.x * 256 + threadIdx.x;
    if (i < 32 * 8320) {
        float s = 0.f;
#pragma unroll
        for (int c = 0; c < 4; ++c) s += Mpart[(size_t)c * 32 * 8320 + i];
        Mbuf[i] = s;
    }
}

// ---------------------------------------------------------------------------
// Q-side apply; writes attn in bf16.
// ---------------------------------------------------------------------------
__global__ __launch_bounds__(256) void qside(
    const float* __restrict__ fq, const float* __restrict__ Mbuf,
    const float* __restrict__ rnq, const float* __restrict__ mq,
    const float* __restrict__ qv, const float* __restrict__ wmix,
    short* __restrict__ attn_out) {
    int ntile = blockIdx.x, hb = blockIdx.y;
    int h = hb >> 2, b = hb & 3;
    __shared__ float M1s[4096], M2s[4096], fqt[16 * 64], Skvs[64], Smks[64];
    __shared__ float rnqs[16], mqs[16], qvs[16];
    int t = threadIdx.x;
    const float* base = Mbuf + (size_t)hb * 8320;
#pragma unroll
    for (int u = 0; u < 16; ++u) {
        M1s[t + u * 256] = base[t + u * 256];
        M2s[t + u * 256] = base[4096 + t + u * 256];
    }
    if (t < 64) {
        Skvs[t] = base[8192 + t];
        Smks[t] = base[8256 + t];
    }
    int n0 = ntile * 16;
#pragma unroll
    for (int u = 0; u < 4; ++u) {
        int idx = t + u * 256;
        int r = idx >> 6, d = idx & 63;
        fqt[idx] = fq[(size_t)(b * 1024 + n0 + r) * 512 + h * 64 + d];
    }
    if (t < 16) {
        int sidx = h * ROWS + b * 1024 + n0 + t;
        rnqs[t] = rnq[sidx];
        mqs[t] = mq[sidx];
        qvs[t] = qv[sidx];
    }
    __syncthreads();
    float cw = wmix[h * 3 + 0], covw = wmix[h * 3 + 1], vw = wmix[h * 3 + 2];
    int e = t & 63, rq = t >> 6;
    float a1[4] = {}, a2[4] = {};
    for (int d = 0; d < 64; ++d) {
        float m1v = M1s[d * 64 + e], m2v = M2s[d * 64 + e];
#pragma unroll
        for (int i = 0; i < 4; ++i) {
            float qd = fqt[(rq * 4 + i) * 64 + d];
            a1[i] += qd * m1v;
            a2[i] += qd * m2v;
        }
    }
    float c2 = covw * (1.f / 64.f), c3 = vw * (1.f / 64.f);
#pragma unroll
    for (int i = 0; i < 4; ++i) {
        int rr = rq * 4 + i;
        float v = cw * rnqs[rr] * a1[i] + c2 * a2[i] + c3 * qvs[rr] * Skvs[e] -
                  covw * mqs[rr] * Smks[e];
        attn_out[(size_t)(b * 1024 + n0 + rr) * 512 + h * 64 + e] = f2bf(v);
    }
}

// ---------------------------------------------------------------------------
extern "C" void kernel_launch(void* const* d_in, const int* in_sizes, int n_in,
                              void* d_out, int out_size, void* d_ws, size_t ws_size,
                              hipStream_t stream) {
    const float* q = (const float*)d_in[0];
    const float* k = (const float*)d_in[1];
    const float* v = (const float*)d_in[2];
    const float* Win = (const float*)d_in[3];
    const float* Wout = (const float*)d_in[4];
    const float* bout = (const float*)d_in[5];
    const float* g1 = (const float*)d_in[6];
    const float* b1n = (const float*)d_in[7];
    const float* g2 = (const float*)d_in[8];
    const float* b2n = (const float*)d_in[9];
    const float* Wup = (const float*)d_in[10];
    const float* bup = (const float*)d_in[11];
    const float* Wdn = (const float*)d_in[12];
    const float* bdn = (const float*)d_in[13];
    const float* wpW1 = (const float*)d_in[14];
    const float* wpb1 = (const float*)d_in[15];
    const float* wpg = (const float*)d_in[16];
    const float* wpb = (const float*)d_in[17];
    const float* wpW2 = (const float*)d_in[18];
    const float* wpb2 = (const float*)d_in[19];
    float* out = (float*)d_out;

    float* wsf = (float*)d_ws;
    // [0, 6291456): fqkv fp32 (3 x 4096 x 512); later reused as hmid bf16
    float* fq = wsf;
    float* fk = wsf + 2097152;
    float* fv = wsf + 2 * 2097152;
    short* hmid = (short*)wsf;  // 4096x2048 bf16 (needs 4194304 float slots)
    // [6291456, 9437184): qkvln bf16 (12288x512); later attnbf + x2bf
    short* qkvln = (short*)(wsf + 6291456);
    short* attnbf = (short*)(wsf + 6291456);            // 4096x512 bf16
    short* x2bf = (short*)(wsf + 6291456 + 1048576);    // 4096x512 bf16
    // [9437184, 10747904): bf16 weights
    short* Winbf = (short*)(wsf + 9437184);
    short* Woutbf = (short*)(wsf + 9437184 + 131072);
    short* Wupbf = (short*)(wsf + 9437184 + 262144);
    short* Wdnbf = (short*)(wsf + 9437184 + 262144 + 524288);
    // stats
    float* S = wsf + 10747904;          // [2][3][32768] head stats
    float* qg = S + 196608;             // 512
    float* kg = qg + 512;               // 512
    float* wmix = kg + 512;             // 32
    float* Mbuf = wmix + 32;            // 32*8320
    float* Mpart = Mbuf + 266240;       // 128*8320
    float* mqS = S, *rnqS = S + 32768, *qvS = S + 65536;
    float* mkS = S + 98304, *rnkS = S + 131072, *kvS = S + 163840;

    // 1. weights -> bf16 ; LN(q/k/v) -> stacked bf16
    wconv<<<dim3(512, 4), 256, 0, stream>>>(Win, Wout, Wup, Wdn,
                                            Winbf, Woutbf, Wupbf, Wdnbf);
    lnconv<<<dim3(1024, 3), 256, 0, stream>>>(q, k, v, g1, b1n, qkvln);

    // 2. stacked projection: fqkv = LN(qkv) @ Win^T  (M=12288)
    mfma_gemm_nt<0, false><<<dim3(4, 96), 256, 0, stream>>>(
        qkvln, Winbf, fq, 12288, 512, 512, nullptr, nullptr);

    // 3. per-(head,row) stats + per-head global means + policy MLP
    head_stats2<<<dim3(4096, 2), 512, 0, stream>>>(fq, fk, S);
    zero_k<<<4, 256, 0, stream>>>(qg, 1024);
    colmean<<<dim3(32, 2), 512, 0, stream>>>(fq, fk, qg, kg);
    policy_mlp<<<8, 64, 0, stream>>>(qg, kg, wpW1, wpb1, wpg, wpb, wpW2, wpb2, wmix);

    // 4. linear-attention K-side reduction (split-4) + Q-side apply
    ksideP<<<dim3(32, 4), 256, 0, stream>>>(fk, fv, rnkS, kvS, mkS, Mpart);
    reduceM<<<1040, 256, 0, stream>>>(Mpart, Mbuf);
    qside<<<dim3(64, 32), 256, 0, stream>>>(fq, Mbuf, rnqS, mqS, qvS, wmix, attnbf);

    // 5. q2 = q + attn @ Wout^T + bout  -> d_out
    mfma_gemm_nt<2, false><<<dim3(4, 32), 256, 0, stream>>>(
        attnbf, Woutbf, out, 4096, 512, 512, bout, q);

    // 6. MLP: x2 = LN(q2); h = gelu(x2@Wup^T+bup); out = q2 + h@Wdn^T + bdn
    lnconv<<<dim3(1024, 1), 256, 0, stream>>>(out, out, out, g2, b2n, x2bf);
    mfma_gemm_nt<3, true><<<dim3(16, 32), 256, 0, stream>>>(
        x2bf, Wupbf, hmid, 4096, 2048, 512, bup, nullptr);
    mfma_gemm_nt<2, false><<<dim3(4, 32), 256, 0, stream>>>(
        hmid, Wdnbf, out, 4096, 512, 2048, bdn, out);
}